// Round 10
// baseline (93.631 us; speedup 1.0000x reference)
//
#include <hip/hip_runtime.h>

#define D     4096
#define NERR  8192
#define DF4   (D / 4)          // 1024 f4 per row
#define TPB   1024
#define RB    32               // rows per block in k1/k3 (512 KB contiguous)
#define NBLK  (NERR / RB)      // 256

typedef float f32x4 __attribute__((ext_vector_type(4)));

// ---------------- k1: per-rowblock column sums of |e| ------------------
// block b: rows [32b, 32b+32). Thread t owns f4-col t for all 32 rows ->
// zero cross-thread reduction. Each block reads 512 KB fully sequentially.
__global__ __launch_bounds__(TPB) void k_rowsum(const f32x4* __restrict__ e4,
                                                f32x4* __restrict__ part4) {
    const int t = threadIdx.x;
    const int b = blockIdx.x;
    const f32x4* p = e4 + (size_t)b * RB * DF4 + t;

    f32x4 acc = (f32x4)(0.f, 0.f, 0.f, 0.f);
    #pragma unroll 8
    for (int r = 0; r < RB; ++r) {
        f32x4 v = p[(size_t)r * DF4];
        acc.x += fabsf(v.x);
        acc.y += fabsf(v.y);
        acc.z += fabsf(v.z);
        acc.w += fabsf(v.w);
    }
    part4[(size_t)b * DF4 + t] = acc;     // 16 KB contiguous per block
}

// ---------------- k2: column-reduce partials + finalize ----------------
// 16 blocks x 1024 threads; block f owns f4-cols [64f, 64f+64).
// Reads the 4 MB partial matrix (L2/L3-hot) with contiguous 1 KB rows.
__global__ __launch_bounds__(TPB) void k_finalize(const f32x4* __restrict__ part4,
                                                  const f32x4* __restrict__ c4,
                                                  f32x4* __restrict__ oc4,
                                                  f32x4* __restrict__ cs4,
                                                  float* __restrict__ mu_arr) {
    __shared__ f32x4 red[16][64];
    const int t   = threadIdx.x;
    const int j   = t & 63;               // local f4-col
    const int rep = t >> 6;               // 0..15
    const int g   = blockIdx.x * 64 + j;  // global f4-col

    f32x4 s = (f32x4)(0.f, 0.f, 0.f, 0.f);
    #pragma unroll
    for (int b = rep; b < NBLK; b += 16) s += part4[(size_t)b * DF4 + g];
    red[rep][j] = s;
    __syncthreads();

    if (t < 64) {
        f32x4 apt = red[0][t];
        #pragma unroll
        for (int rr = 1; rr < 16; ++rr) apt += red[rr][t];
        const int gg = blockIdx.x * 64 + t;
        const f32x4 cen = c4[gg];
        f32x4 oc, cs;
        #pragma unroll
        for (int k = 0; k < 4; ++k) {
            const float c  = cen[k];
            const float ub = c + apt[k];
            const float lb = c - apt[k];
            const bool cross = (ub > 0.f) && (lb < 0.f);
            const bool act   = (lb >= 0.f);
            const float denom = cross ? (ub - lb) : 1.f;
            const float slope = cross ? (ub / denom) : 0.f;
            const float mu    = cross ? (-slope * lb * 0.5f) : 0.f;
            oc[k] = act ? c : (slope * c + mu);
            cs[k] = act ? 1.f : slope;
            mu_arr[4 * gg + k] = mu;
        }
        oc4[gg] = oc;
        cs4[gg] = cs;
    }
}

// ---------------- k3: top = e*scale (NT) + bottom fill with diag mu ----
// block b: top rows [32b, 32b+32) fully sequential (read L3-resident e,
// NT-write top), then bottom rows [16b, 16b+16) sequential NT zero-fill
// with the diagonal element = mu.
__global__ __launch_bounds__(TPB) void k_emit(const f32x4* __restrict__ e4,
                                              const f32x4* __restrict__ cs4,
                                              const float* __restrict__ mu_arr,
                                              f32x4* __restrict__ top4,
                                              f32x4* __restrict__ bot4) {
    const int t = threadIdx.x;
    const int b = blockIdx.x;
    const f32x4 s = cs4[t];               // thread t owns f4-col t
    const size_t base = (size_t)b * RB * DF4;

    #pragma unroll 8
    for (int r = 0; r < RB; ++r) {
        const size_t idx = base + (size_t)r * DF4 + t;
        f32x4 v = e4[idx];
        v *= s;
        __builtin_nontemporal_store(v, &top4[idx]);
    }

    const int r0 = b * 16;
    #pragma unroll
    for (int j = 0; j < 16; ++j) {
        const int r  = r0 + j;
        const int dg = r >> 2;            // diag f4-col of row r
        f32x4 v = (f32x4)(0.f, 0.f, 0.f, 0.f);
        if (t == dg) v[r & 3] = mu_arr[r];
        __builtin_nontemporal_store(v, &bot4[(size_t)r * DF4 + t]);
    }
}

extern "C" void kernel_launch(void* const* d_in, const int* in_sizes, int n_in,
                              void* d_out, int out_size, void* d_ws, size_t ws_size,
                              hipStream_t stream) {
    const float* center = (const float*)d_in[0];   // (4096,)
    const float* error  = (const float*)d_in[1];   // (8192, 4096)
    float* out = (float*)d_out;
    float* ws  = (float*)d_ws;

    // ws (floats): [part: 256*4096 = 4 MB][col_scale: 4096][mu: 4096]
    float* part      = ws;
    float* col_scale = ws + (size_t)NBLK * D;
    float* mu_arr    = col_scale + D;

    float* out_center = out;                                   // (4096,)
    float* out_top    = out + D;                               // (8192, 4096)
    float* out_bottom = out + (size_t)D + (size_t)NERR * D;    // (4096, 4096)

    k_rowsum<<<NBLK, TPB, 0, stream>>>(
        (const f32x4*)error, (f32x4*)part);
    k_finalize<<<16, TPB, 0, stream>>>(
        (const f32x4*)part, (const f32x4*)center,
        (f32x4*)out_center, (f32x4*)col_scale, mu_arr);
    k_emit<<<NBLK, TPB, 0, stream>>>(
        (const f32x4*)error, (const f32x4*)col_scale, mu_arr,
        (f32x4*)out_top, (f32x4*)out_bottom);
}

// Round 11
// 88.590 us; speedup vs baseline: 1.0569x; 1.0569x over previous
//
#include <hip/hip_runtime.h>

#define D      4096
#define NERR   8192
#define DF4    (D / 4)          // 1024 f4 per row
#define HROWS  (NERR / 2)       // 4096 rows per half
#define TPB    1024
#define RPP    (TPB / 8)        // 128 rows per pass
#define NPASS  (HROWS / RPP)    // 32 passes
#define NWAVE  (TPB / 64)       // 16
#define NBLK   256

typedef float f32x4 __attribute__((ext_vector_type(4)));

// One dispatch. Block b: strip s=b>>1 (f4-cols 8s..8s+8 = 32 cols, 128 B/row),
// half h=b&1 (rows 4096h..+4096). R9's decomposition (best measured), with the
// three kernels fused via a pair-wise device-scope sync on bar[s].
__global__ __launch_bounds__(TPB) void k_fused(const f32x4* __restrict__ e4,
                                               const f32x4* __restrict__ c4,
                                               f32x4* __restrict__ oc4,
                                               f32x4* __restrict__ top4,
                                               f32x4* __restrict__ bot4,
                                               float* __restrict__ partf,
                                               int*   __restrict__ bar) {
    __shared__ f32x4 wred[NWAVE * 8];
    __shared__ float aptL[32];
    __shared__ f32x4 scl[8];
    __shared__ f32x4 muL[8];

    const int t    = threadIdx.x;
    const int lane = t & 63;
    const int w    = t >> 6;
    const int cf   = t & 7;             // f4-col within strip
    const int r0   = t >> 3;            // row within pass, 0..127
    const int s    = blockIdx.x >> 1;
    const int h    = blockIdx.x & 1;
    const int off  = s * 8 + cf;
    const size_t rbase = (size_t)h * HROWS;

    // ---- phase 1: |e| column sums over the strip-half (allocate e in L3)
    f32x4 acc = (f32x4)(0.f, 0.f, 0.f, 0.f);
    #pragma unroll 8
    for (int k = 0; k < NPASS; ++k) {
        f32x4 v = e4[(rbase + k * RPP + r0) * DF4 + off];
        acc.x += fabsf(v.x);
        acc.y += fabsf(v.y);
        acc.z += fabsf(v.z);
        acc.w += fabsf(v.w);
    }
    #pragma unroll
    for (int st = 8; st <= 32; st <<= 1) {
        acc.x += __shfl_xor(acc.x, st, 64);
        acc.y += __shfl_xor(acc.y, st, 64);
        acc.z += __shfl_xor(acc.z, st, 64);
        acc.w += __shfl_xor(acc.w, st, 64);
    }
    if (lane < 8) wred[w * 8 + lane] = acc;
    __syncthreads();

    // 32 threads publish one float each of this half's 32-float partial,
    // device-scope (bypasses stale-cache hazards across XCDs).
    if (t < 32) {
        const int f4 = t >> 2, cm = t & 3;
        float sum = 0.f;
        #pragma unroll
        for (int w2 = 0; w2 < NWAVE; ++w2) sum += wred[w2 * 8 + f4][cm];
        __hip_atomic_store(&partf[(2 * s + h) * 32 + t], sum,
                           __ATOMIC_RELAXED, __HIP_MEMORY_SCOPE_AGENT);
    }
    __syncthreads();

    // ---- pair sync: arrive (release), spin until both halves arrived
    if (t == 0) {
        __threadfence();
        __hip_atomic_fetch_add(&bar[s], 1, __ATOMIC_RELEASE,
                               __HIP_MEMORY_SCOPE_AGENT);
        while (__hip_atomic_load(&bar[s], __ATOMIC_ACQUIRE,
                                 __HIP_MEMORY_SCOPE_AGENT) < 2) {}
    }
    __syncthreads();

    if (t < 32)
        aptL[t] = __hip_atomic_load(&partf[(2 * s) * 32 + t],
                                    __ATOMIC_RELAXED, __HIP_MEMORY_SCOPE_AGENT)
                + __hip_atomic_load(&partf[(2 * s + 1) * 32 + t],
                                    __ATOMIC_RELAXED, __HIP_MEMORY_SCOPE_AGENT);
    __syncthreads();

    // ---- finalize (redundant in both halves; 8 threads x 4 cols)
    if (t < 8) {
        const int g = s * 8 + t;
        const f32x4 cen = c4[g];
        f32x4 oc, cs, mu4;
        #pragma unroll
        for (int j = 0; j < 4; ++j) {
            const float apt = aptL[t * 4 + j];
            const float c  = cen[j];
            const float ub = c + apt;
            const float lb = c - apt;
            const bool cross = (ub > 0.f) && (lb < 0.f);
            const bool act   = (lb >= 0.f);
            const float denom = cross ? (ub - lb) : 1.f;
            const float slope = cross ? (ub / denom) : 0.f;
            const float mu    = cross ? (-slope * lb * 0.5f) : 0.f;
            oc[j]  = act ? c : (slope * c + mu);
            cs[j]  = act ? 1.f : slope;
            mu4[j] = mu;
        }
        scl[t] = cs;
        muL[t] = mu4;
        if (h == 0) oc4[g] = oc;
    }
    __syncthreads();

    // ---- phase 2: re-read own strip-half (L3-resident), scale, NT store
    const f32x4 cs = scl[cf];
    #pragma unroll 8
    for (int k = 0; k < NPASS; ++k) {
        const size_t idx = (rbase + k * RPP + r0) * DF4 + off;
        f32x4 v = e4[idx];
        v *= cs;
        __builtin_nontemporal_store(v, &top4[idx]);
    }

    // ---- bottom rows [32s+16h, +16): one wave per row; diag f4 = mu
    const int r  = 32 * s + 16 * h + w;
    const int dg = r >> 2;                      // diag f4-col of row r
    const float muv = muL[(r >> 2) - 8 * s][r & 3];
    #pragma unroll
    for (int j = 0; j < 16; ++j) {
        const int c = lane + j * 64;
        f32x4 v = (f32x4)(0.f, 0.f, 0.f, 0.f);
        if (c == dg) v[r & 3] = muv;
        __builtin_nontemporal_store(v, &bot4[(size_t)r * DF4 + c]);
    }
}

extern "C" void kernel_launch(void* const* d_in, const int* in_sizes, int n_in,
                              void* d_out, int out_size, void* d_ws, size_t ws_size,
                              hipStream_t stream) {
    const float* center = (const float*)d_in[0];   // (4096,)
    const float* error  = (const float*)d_in[1];   // (8192, 4096)
    float* out = (float*)d_out;
    float* ws  = (float*)d_ws;

    // ws: [partf: 256*32 floats = 32 KB][bar: 128 ints]
    float* partf = ws;
    int*   bar   = (int*)(ws + 256 * 32);

    float* out_center = out;                                   // (4096,)
    float* out_top    = out + D;                               // (8192, 4096)
    float* out_bottom = out + (size_t)D + (size_t)NERR * D;    // (4096, 4096)

    // Counters must be 0 at kernel start on every call (ws is poisoned 0xAA
    // once and never re-poisoned; a stale/garbage counter would break the
    // spin). Tiny async memset is graph-capture-safe.
    hipMemsetAsync(bar, 0, 128 * sizeof(int), stream);

    k_fused<<<NBLK, TPB, 0, stream>>>(
        (const f32x4*)error, (const f32x4*)center,
        (f32x4*)out_center, (f32x4*)out_top, (f32x4*)out_bottom,
        partf, bar);
}

// Round 12
// 74.414 us; speedup vs baseline: 1.2583x; 1.1905x over previous
//
#include <hip/hip_runtime.h>

#define D      4096
#define NERR   8192
#define DF4    (D / 4)          // 1024 f4 per row
#define QROWS  (NERR / 4)       // 2048 rows per quarter
#define TPB    1024
#define RPP    (TPB / 8)        // 128 rows per pass
#define NPASS  (QROWS / RPP)    // 16 passes
#define NWAVE  (TPB / 64)       // 16
#define NBLK   512              // strip (128) x quarter (4)

typedef float f32x4 __attribute__((ext_vector_type(4)));

// ---------------- k1: partial column sums of |e| -----------------------
// block b: strip s=b>>2 (f4-cols 8s..8s+8 = 32 cols = one 128B line/row),
// quarter q=b&3 (rows 2048q..+2048). 2 blocks/CU -> 32 waves/CU in-flight.
__global__ __launch_bounds__(TPB) void k_reduce(const f32x4* __restrict__ e4,
                                                float* __restrict__ partf) {
    __shared__ f32x4 wred[NWAVE * 8];

    const int t    = threadIdx.x;
    const int lane = t & 63;
    const int w    = t >> 6;
    const int cf   = t & 7;             // f4-col within strip
    const int r0   = t >> 3;            // row within pass, 0..127
    const int s    = blockIdx.x >> 2;
    const int q    = blockIdx.x & 3;
    const int off  = s * 8 + cf;
    const size_t rbase = (size_t)q * QROWS;

    f32x4 acc = (f32x4)(0.f, 0.f, 0.f, 0.f);
    #pragma unroll 8
    for (int k = 0; k < NPASS; ++k) {
        f32x4 v = e4[(rbase + k * RPP + r0) * DF4 + off];
        acc.x += fabsf(v.x);
        acc.y += fabsf(v.y);
        acc.z += fabsf(v.z);
        acc.w += fabsf(v.w);
    }
    // reduce over row bits within the wave (lane bits 3..5)
    #pragma unroll
    for (int st = 8; st <= 32; st <<= 1) {
        acc.x += __shfl_xor(acc.x, st, 64);
        acc.y += __shfl_xor(acc.y, st, 64);
        acc.z += __shfl_xor(acc.z, st, 64);
        acc.w += __shfl_xor(acc.w, st, 64);
    }
    if (lane < 8) wred[w * 8 + lane] = acc;
    __syncthreads();

    if (t < 32) {                       // 32 floats = this block's partial
        const int f4 = t >> 2, cm = t & 3;
        float sum = 0.f;
        #pragma unroll
        for (int w2 = 0; w2 < NWAVE; ++w2) sum += wred[w2 * 8 + f4][cm];
        partf[(size_t)blockIdx.x * 32 + t] = sum;
    }
}

// ---------------- k2: finalize + scaled top + bottom fill --------------
// Same decomposition. Finalize redundantly per strip (reads 4x128B).
// Top re-read is IF$-resident (FETCH stays ~134 MB). Bottom: 8 rows/block.
__global__ __launch_bounds__(TPB) void k_emit(const f32x4* __restrict__ e4,
                                              const float* __restrict__ partf,
                                              const f32x4* __restrict__ c4,
                                              f32x4* __restrict__ oc4,
                                              f32x4* __restrict__ top4,
                                              f32x4* __restrict__ bot4) {
    __shared__ float aptL[32];
    __shared__ f32x4 scl[8];
    __shared__ f32x4 muL[8];

    const int t    = threadIdx.x;
    const int lane = t & 63;
    const int w    = t >> 6;
    const int cf   = t & 7;
    const int r0   = t >> 3;
    const int s    = blockIdx.x >> 2;
    const int q    = blockIdx.x & 3;
    const int off  = s * 8 + cf;
    const size_t rbase = (size_t)q * QROWS;

    if (t < 32) {
        float a = 0.f;
        #pragma unroll
        for (int qq = 0; qq < 4; ++qq)
            a += partf[(size_t)(s * 4 + qq) * 32 + t];
        aptL[t] = a;
    }
    __syncthreads();

    if (t < 8) {                        // one f4-col (4 columns) each
        const int g = s * 8 + t;
        const f32x4 cen = c4[g];
        f32x4 oc, cs, mu4;
        #pragma unroll
        for (int j = 0; j < 4; ++j) {
            const float apt = aptL[t * 4 + j];
            const float c  = cen[j];
            const float ub = c + apt;
            const float lb = c - apt;
            const bool cross = (ub > 0.f) && (lb < 0.f);
            const bool act   = (lb >= 0.f);
            const float denom = cross ? (ub - lb) : 1.f;
            const float slope = cross ? (ub / denom) : 0.f;
            const float mu    = cross ? (-slope * lb * 0.5f) : 0.f;
            oc[j]  = act ? c : (slope * c + mu);
            cs[j]  = act ? 1.f : slope;
            mu4[j] = mu;
        }
        scl[t] = cs;
        muL[t] = mu4;
        if (q == 0) oc4[g] = oc;
    }
    __syncthreads();

    // ---- top: re-read own strip-quarter (IF$ hit), scale, NT store
    const f32x4 cs = scl[cf];
    #pragma unroll 8
    for (int k = 0; k < NPASS; ++k) {
        const size_t idx = (rbase + k * RPP + r0) * DF4 + off;
        f32x4 v = e4[idx];
        v *= cs;
        __builtin_nontemporal_store(v, &top4[idx]);
    }

    // ---- bottom rows [32s+8q, +8): 2 waves per row; diag f4 = mu
    const int r  = 32 * s + 8 * q + (w >> 1);
    const int dg = r >> 2;                      // diag f4-col of row r
    const float muv = muL[(r >> 2) - 8 * s][r & 3];
    #pragma unroll
    for (int j = 0; j < 8; ++j) {
        const int c = (w & 1) * 512 + lane + j * 64;
        f32x4 v = (f32x4)(0.f, 0.f, 0.f, 0.f);
        if (c == dg) v[r & 3] = muv;
        __builtin_nontemporal_store(v, &bot4[(size_t)r * DF4 + c]);
    }
}

extern "C" void kernel_launch(void* const* d_in, const int* in_sizes, int n_in,
                              void* d_out, int out_size, void* d_ws, size_t ws_size,
                              hipStream_t stream) {
    const float* center = (const float*)d_in[0];   // (4096,)
    const float* error  = (const float*)d_in[1];   // (8192, 4096)
    float* out = (float*)d_out;

    float* out_center = out;                                   // (4096,)
    float* out_top    = out + D;                               // (8192, 4096)
    float* out_bottom = out + (size_t)D + (size_t)NERR * D;    // (4096, 4096)

    float* partf = (float*)d_ws;   // 512 blocks x 32 floats = 64 KB

    k_reduce<<<NBLK, TPB, 0, stream>>>(
        (const f32x4*)error, partf);
    k_emit<<<NBLK, TPB, 0, stream>>>(
        (const f32x4*)error, partf, (const f32x4*)center,
        (f32x4*)out_center, (f32x4*)out_top, (f32x4*)out_bottom);
}